// Round 10
// baseline (346.441 us; speedup 1.0000x reference)
//
#include <hip/hip_runtime.h>

// GraphConvolution: out = segment_sum(edge_val * (x@W)[edge_col], edge_row) + b
// M=100000 nodes, K=256 in_feats, N=128 out_feats, E=1.6M edges. fp32 in/out.
//
// R9 (329.3us): barrier-free gemm fused with edge partition (mod-RMOD roles).
// R11 (317.5us): sort-in-LDS bucket_spmm. R12 (312.8): 512t spmm buckets.
// R14 (304.1us): LDS-B gemm -- FLAT (116us). B-throughput theory DISPROVEN:
//   all gemm variants sit at 87-116us, MfmaUtil 2%, HBM 12%, occ 14%, moving
//   exactly the ideal 113MB but 4-5x slower than the 25us roofline.
//   => pure concurrency shortfall (3 waves/SIMD, bursty dependent A-loads).
// R15: MLP attack. 64-row tiles (wave owns 16 rows, acc 32 AGPR not 64);
//   distance-4 A-prefetch ring ca[4][2] (32 VGPR, statically indexed under
//   full unroll) -> 8 independent 16B loads in flight per lane sustained.
//   B back to direct-global (L2-hot; LDS-B proved useless). Grid ~1759
//   blocks (~7/CU) for balance. Partition + bucket_spmm unchanged (proven).

#define K_FEATS 256
#define N_FEATS 128
#define BSHIFT 7                 // 128 rows per bucket (partition + spmm)
#define BROWS 128
#define BCAP 3072                // mean 2048, +22 sigma
#define STASH 6                  // BCAP / 512
#define CHUNK 8192
#define EPT 32                   // edges per thread (256 threads)
#define RMOD 9                   // 1 of every RMOD blocks is a partition block

typedef __attribute__((ext_vector_type(8))) short short8;
typedef __attribute__((ext_vector_type(4))) float float4v;

__device__ __forceinline__ unsigned short f2bf(float f) {
    unsigned int u = __float_as_uint(f);
    unsigned int r = u + 0x7FFF + ((u >> 16) & 1);   // round-to-nearest-even
    return (unsigned short)(r >> 16);
}

// ---------------- prep: Wt[n][k] bf16 from w[k][n] fp32 ----------------
__global__ __launch_bounds__(256) void prep_w(const float* __restrict__ w,
                                              unsigned short* __restrict__ wt) {
    int n = blockIdx.x;
    int k = threadIdx.x;
    wt[n * K_FEATS + k] = f2bf(w[k * N_FEATS + n]);
}

__global__ __launch_bounds__(256) void zero_ints(int* __restrict__ p, int n) {
    int i = blockIdx.x * 256 + threadIdx.x;
    if (i < n) p[i] = 0;
}

// ---------------- fused: high-MLP GEMM + edge partition ----------------
// blockIdx % RMOD == 0 -> partition chunk; else gemm tile (64 rows).
__global__ __launch_bounds__(256) void gemm_partition(
        const float* __restrict__ x, const unsigned short* __restrict__ wt,
        unsigned short* __restrict__ sup, int M, int NT,
        const int* __restrict__ erow, const int* __restrict__ ecol,
        const float* __restrict__ eval_, int* __restrict__ bcur,
        int2* __restrict__ tmp, int E, int NB, int NCH) {
    __shared__ int hist[1024];
    __shared__ int cur[1024];
    const int g   = blockIdx.x;
    const int tid = threadIdx.x;

    if (g % RMOD == 0) {
        // ---------- partition role ----------
        int pid = g / RMOD;
        if (pid >= NCH) return;
        const long e0 = (long)pid * CHUNK;

        for (int i = tid; i < NB; i += 256) hist[i] = 0;
        __syncthreads();

        int rows[EPT];
#pragma unroll
        for (int i = 0; i < EPT; i++) {
            long e = e0 + tid + i * 256;
            int r = -1;
            if (e < E) {
                r = erow[e];
                atomicAdd(&hist[r >> BSHIFT], 1);
            }
            rows[i] = r;
        }
        __syncthreads();

        // one global reservation per touched bucket
        for (int i = tid; i < NB; i += 256) {
            int c = hist[i];
            cur[i] = c ? atomicAdd(&bcur[i], c) : 0;
        }
        __syncthreads();

        // place edges: LDS cursor gives offset within this WG's reserved run
#pragma unroll
        for (int i = 0; i < EPT; i++) {
            long e = e0 + tid + i * 256;
            if (e >= E) continue;
            int r = rows[i];
            int b = r >> BSHIFT;
            int p = atomicAdd(&cur[b], 1);
            if (p < BCAP)
                tmp[(long)b * BCAP + p] = make_int2(((r & (BROWS - 1)) << 17) | ecol[e],
                                                    __float_as_int(eval_[e]));
        }
        return;
    }

    // ---------- gemm role: wave owns 16 rows; distance-4 A-prefetch ring ----
    int tile = g - g / RMOD - 1;
    if (tile >= NT) return;

    const int wv   = tid >> 6;
    const int lane = tid & 63;
    const int l15  = lane & 15;
    const int quad = lane >> 4;
    const int row0 = tile * 64 + wv * 16;    // this wave's 16 rows
    const int grow = row0 + l15;
    const bool ok  = grow < M;
    const float* pA = x + (long)grow * K_FEATS + quad * 8;
    const float4 z4 = make_float4(0.f, 0.f, 0.f, 0.f);

    float4v acc[8];
#pragma unroll
    for (int nt = 0; nt < 8; nt++) acc[nt] = (float4v)(0.f);

    // prologue: fill 4-deep A ring (8 independent 16B loads in flight)
    float4 ca[4][2];
#pragma unroll
    for (int s = 0; s < 4; s++) {
        ca[s][0] = ok ? *(const float4*)(pA + s * 32)     : z4;
        ca[s][1] = ok ? *(const float4*)(pA + s * 32 + 4) : z4;
    }

#pragma unroll
    for (int s = 0; s < 8; s++) {
        const int k0 = s * 32;
        // convert this step's A, then immediately reuse the slot for s+4
        short8 af;
        af[0] = (short)f2bf(ca[s & 3][0].x); af[1] = (short)f2bf(ca[s & 3][0].y);
        af[2] = (short)f2bf(ca[s & 3][0].z); af[3] = (short)f2bf(ca[s & 3][0].w);
        af[4] = (short)f2bf(ca[s & 3][1].x); af[5] = (short)f2bf(ca[s & 3][1].y);
        af[6] = (short)f2bf(ca[s & 3][1].z); af[7] = (short)f2bf(ca[s & 3][1].w);
        if (s < 4) {
            ca[s & 3][0] = ok ? *(const float4*)(pA + (s + 4) * 32)     : z4;
            ca[s & 3][1] = ok ? *(const float4*)(pA + (s + 4) * 32 + 4) : z4;
        }
        short8 bfrag[8];
#pragma unroll
        for (int nt = 0; nt < 8; nt++) {
            bfrag[nt] = *(const short8*)(wt + (nt * 16 + l15) * K_FEATS + k0 + quad * 8);
        }
#pragma unroll
        for (int nt = 0; nt < 8; nt++)
            acc[nt] = __builtin_amdgcn_mfma_f32_16x16x32_bf16(af, bfrag[nt], acc[nt], 0, 0, 0);
    }

#pragma unroll
    for (int reg = 0; reg < 4; reg++) {
        int gr = row0 + quad * 4 + reg;
        if (gr < M) {
#pragma unroll
            for (int nt = 0; nt < 8; nt++) {
                sup[(long)gr * N_FEATS + nt * 16 + l15] = f2bf(acc[nt][reg]);
            }
        }
    }
}

// ---------------- fused sort+spmm: 512 threads per 128-row bucket -----------
// Phase A: tmp edges -> register stash + LDS hist; 128-scan; place into LDS
// sorted array. Phase B: wave per 16 rows, split-wave gather (8 in flight).
__global__ __launch_bounds__(512) void bucket_spmm(const int* __restrict__ bcnt,
                                                   const int2* __restrict__ tmp,
                                                   const unsigned short* __restrict__ sup,
                                                   const float* __restrict__ b,
                                                   float* __restrict__ out, int M) {
    __shared__ int hist[BROWS];
    __shared__ int rs[BROWS];
    __shared__ int cur[BROWS];
    __shared__ __align__(16) int2 se[BCAP];      // 24 KB
    const int bkt  = blockIdx.x;
    const int tid  = threadIdx.x;
    const int wv   = tid >> 6;
    const int lane = tid & 63;
    const int row0 = bkt << BSHIFT;

    if (tid < BROWS) hist[tid] = 0;
    __syncthreads();

    int cnt = bcnt[bkt];
    if (cnt > BCAP) cnt = BCAP;
    const int2* t = tmp + (long)bkt * BCAP;

    // Phase A1: single global read of bucket edges -> stash + histogram
    int2 stash[STASH];
#pragma unroll
    for (int j = 0; j < STASH; j++) {
        int i = tid + j * 512;
        if (i < cnt) {
            int2 e = t[i];
            stash[j] = e;
            atomicAdd(&hist[(unsigned)e.x >> 17], 1);
        }
    }
    __syncthreads();

    // Phase A2: exclusive scan of 128 row counts
    if (tid < BROWS) cur[tid] = hist[tid];
    __syncthreads();
#pragma unroll
    for (int s = 1; s < BROWS; s <<= 1) {
        int v = 0;
        if (tid >= s && tid < BROWS) v = cur[tid - s];
        __syncthreads();
        if (tid < BROWS) cur[tid] += v;
        __syncthreads();
    }
    if (tid < BROWS) {
        int start = cur[tid] - hist[tid];        // exclusive
        rs[tid]  = start;
        cur[tid] = start;
    }
    __syncthreads();

    // Phase A3: place edges into LDS sorted array (col stripped of row bits)
#pragma unroll
    for (int j = 0; j < STASH; j++) {
        int i = tid + j * 512;
        if (i < cnt) {
            int2 e = stash[j];
            int rl = (unsigned)e.x >> 17;
            int p = atomicAdd(&cur[rl], 1);
            se[p] = make_int2(e.x & 0x1FFFF, e.y);
        }
    }
    __syncthreads();

    // Phase B: wave per 16 rows, split-wave gather (8 in flight)
    const int half = lane >> 5;
    const int l31  = lane & 31;
    const uint2* sup64 = (const uint2*)sup;      // 4 bf16 per uint2
    const float4v bb = ((const float4v*)b)[l31];

    for (int rr = 0; rr < 16; rr++) {
        int r    = wv * 16 + rr;
        int grow = row0 + r;
        if (grow >= M) break;                    // only trims the last bucket
        int s  = rs[r];
        int e2 = s + hist[r];

        float4v acc = (float4v)(0.f);
        int base = s;
        for (; base + 8 <= e2; base += 8) {
            int2 ed[4];
#pragma unroll
            for (int u = 0; u < 4; u++) ed[u] = se[base + half + 2 * u];
            uint2 g[4];
#pragma unroll
            for (int u = 0; u < 4; u++) g[u] = sup64[(long)ed[u].x * 32 + l31];
#pragma unroll
            for (int u = 0; u < 4; u++) {
                float v = __int_as_float(ed[u].y);
                acc.x += v * __uint_as_float(g[u].x << 16);
                acc.y += v * __uint_as_float(g[u].x & 0xFFFF0000u);
                acc.z += v * __uint_as_float(g[u].y << 16);
                acc.w += v * __uint_as_float(g[u].y & 0xFFFF0000u);
            }
        }
        for (int i = base + half; i < e2; i += 2) {
            int2 ed = se[i];
            uint2 g = sup64[(long)ed.x * 32 + l31];
            float v = __int_as_float(ed.y);
            acc.x += v * __uint_as_float(g.x << 16);
            acc.y += v * __uint_as_float(g.x & 0xFFFF0000u);
            acc.z += v * __uint_as_float(g.y << 16);
            acc.w += v * __uint_as_float(g.y & 0xFFFF0000u);
        }

        // cross-half reduce: half 1's partials fold into half 0
        acc.x += __shfl_xor(acc.x, 32);
        acc.y += __shfl_xor(acc.y, 32);
        acc.z += __shfl_xor(acc.z, 32);
        acc.w += __shfl_xor(acc.w, 32);

        if (half == 0) {
            float4v o = acc + bb;
            *(float4v*)(out + (long)grow * N_FEATS + l31 * 4) = o;
        }
    }
}

extern "C" void kernel_launch(void* const* d_in, const int* in_sizes, int n_in,
                              void* d_out, int out_size, void* d_ws, size_t ws_size,
                              hipStream_t stream) {
    const float* x     = (const float*)d_in[0];
    const int*   erow  = (const int*)d_in[1];
    const int*   ecol  = (const int*)d_in[2];
    const float* eval_ = (const float*)d_in[3];
    const float* w     = (const float*)d_in[4];
    const float* b     = (const float*)d_in[5];
    float* out = (float*)d_out;

    const int M   = in_sizes[0] / K_FEATS;     // 100000
    const int E   = in_sizes[1];               // 1600000
    const int NB  = (M + BROWS - 1) >> BSHIFT; // 782 (partition/spmm buckets)
    const int NT  = (M + 63) / 64;             // 1563 gemm tiles (64 rows)
    const int NCH = (E + CHUNK - 1) / CHUNK;   // 196 partition chunks

    // workspace layout (16B aligned)
    size_t o_sup  = 0;                                               // bf16 sup
    size_t o_wt   = o_sup  + (((size_t)M * N_FEATS * 2 + 15) & ~15ul);
    size_t o_bcur = o_wt   + (size_t)K_FEATS * N_FEATS * 2;
    size_t o_tmp  = o_bcur + (((size_t)NB * 4 + 15) & ~15ul);

    unsigned short* sup  = (unsigned short*)((char*)d_ws + o_sup);
    unsigned short* wt   = (unsigned short*)((char*)d_ws + o_wt);
    int*            bcur = (int*)((char*)d_ws + o_bcur);
    int2*           tmp  = (int2*)((char*)d_ws + o_tmp);

    prep_w<<<N_FEATS, 256, 0, stream>>>(w, wt);
    zero_ints<<<(NB + 255) / 256, 256, 0, stream>>>(bcur, NB);

    // fused dense GEMM + sparse partition (independent until bucket_spmm)
    gemm_partition<<<NT + NCH, 256, 0, stream>>>(x, wt, sup, M, NT,
                                                 erow, ecol, eval_, bcur, tmp, E, NB, NCH);

    // sort-in-LDS + gather + out, one kernel, no global sedge
    bucket_spmm<<<NB, 512, 0, stream>>>(bcur, tmp, sup, b, out, M);
}

// Round 11
// 332.285 us; speedup vs baseline: 1.0426x; 1.0426x over previous
//
#include <hip/hip_runtime.h>

// GraphConvolution: out = segment_sum(edge_val * (x@W)[edge_col], edge_row) + b
// M=100000 nodes, K=256 in_feats, N=128 out_feats, E=1.6M edges. fp32 in/out.
//
// R11 (317.5us): sort-in-LDS bucket_spmm. R12 (312.8): 512t spmm buckets.
// R14 (304.1us): LDS-B gemm FLAT -> B-throughput not the limit.
// R15 FAILED (346us): 16-row waves (2x B-instrs) + more occupancy = WORSE.
//   Conclusion: gemm time tracks per-wave load instrs + per-k-step
//   load->f2bf->MFMA dependence; f2bf VALU (64/k-step) rivals MFMA time;
//   A-loads uncoalesced (lanes 1KB apart).
// R16: (a) pre-convert x->bf16 (xb) in a streaming pass FUSED with edge
//   partition (partition hides under it); gemm inner loop loses all f2bf.
//   (b) gemm stages A-tile via global_load_lds width=16 (async, coalesced),
//   XOR-swizzled by pre-swizzling the GLOBAL source (linear LDS dest, rule
//   #21); afrag ds_read_b128 spreads 8-per-bank-group = optimal. B stays
//   direct-global (R14 proved LDS-B neutral). m97-shape inner loop.

#define K_FEATS 256
#define N_FEATS 128
#define BSHIFT 7                 // 128 rows per bucket (partition + spmm)
#define BROWS 128
#define BCAP 3072                // mean 2048, +22 sigma
#define STASH 6                  // BCAP / 512
#define CHUNK 8192
#define EPT 32                   // edges per thread (256 threads)
#define RMOD 5                   // 1 of every RMOD blocks is a partition block

typedef __attribute__((ext_vector_type(8))) short short8;
typedef __attribute__((ext_vector_type(4))) float float4v;

typedef const unsigned int __attribute__((address_space(1)))* gld_src_t;
typedef unsigned int __attribute__((address_space(3)))* gld_dst_t;

__device__ __forceinline__ unsigned short f2bf(float f) {
    unsigned int u = __float_as_uint(f);
    unsigned int r = u + 0x7FFF + ((u >> 16) & 1);   // round-to-nearest-even
    return (unsigned short)(r >> 16);
}

// ---------------- prep: Wt[n][k] bf16 from w[k][n] fp32 ----------------
__global__ __launch_bounds__(256) void prep_w(const float* __restrict__ w,
                                              unsigned short* __restrict__ wt) {
    int n = blockIdx.x;
    int k = threadIdx.x;
    wt[n * K_FEATS + k] = f2bf(w[k * N_FEATS + n]);
}

__global__ __launch_bounds__(256) void zero_ints(int* __restrict__ p, int n) {
    int i = blockIdx.x * 256 + threadIdx.x;
    if (i < n) p[i] = 0;
}

// ---------------- fused: x->bf16 convert + edge partition ----------------
// blockIdx % RMOD == 0 -> partition chunk; else convert tile (128 rows).
// Both streaming/memory-bound; partition hides under the convert traffic.
__global__ __launch_bounds__(256) void conv_partition(
        const float* __restrict__ x, unsigned short* __restrict__ xb, int M,
        const int* __restrict__ erow, const int* __restrict__ ecol,
        const float* __restrict__ eval_, int* __restrict__ bcur,
        int2* __restrict__ tmp, int E, int NB, int NCH) {
    __shared__ int hist[1024];
    __shared__ int cur[1024];
    const int g   = blockIdx.x;
    const int tid = threadIdx.x;

    if (g % RMOD == 0) {
        // ---------- partition role ----------
        int pid = g / RMOD;
        if (pid >= NCH) return;
        const long e0 = (long)pid * CHUNK;

        for (int i = tid; i < NB; i += 256) hist[i] = 0;
        __syncthreads();

        int rows[EPT];
#pragma unroll
        for (int i = 0; i < EPT; i++) {
            long e = e0 + tid + i * 256;
            int r = -1;
            if (e < E) {
                r = erow[e];
                atomicAdd(&hist[r >> BSHIFT], 1);
            }
            rows[i] = r;
        }
        __syncthreads();

        for (int i = tid; i < NB; i += 256) {
            int c = hist[i];
            cur[i] = c ? atomicAdd(&bcur[i], c) : 0;
        }
        __syncthreads();

#pragma unroll
        for (int i = 0; i < EPT; i++) {
            long e = e0 + tid + i * 256;
            if (e >= E) continue;
            int r = rows[i];
            int b = r >> BSHIFT;
            int p = atomicAdd(&cur[b], 1);
            if (p < BCAP)
                tmp[(long)b * BCAP + p] = make_int2(((r & (BROWS - 1)) << 17) | ecol[e],
                                                    __float_as_int(eval_[e]));
        }
        return;
    }

    // ---------- convert role: 128 rows fp32 -> bf16 (pad rows zeroed) ----
    int tile = g - g / RMOD - 1;
    const int row0 = tile * 128;
#pragma unroll
    for (int j = 0; j < 16; j++) {
        long idx  = (long)row0 * K_FEATS + j * 2048 + tid * 8;
        int  grow = row0 + j * 8 + (tid >> 5);
        short8 o;
        if (grow < M) {
            float4 v0 = *(const float4*)(x + idx);
            float4 v1 = *(const float4*)(x + idx + 4);
            o[0] = (short)f2bf(v0.x); o[1] = (short)f2bf(v0.y);
            o[2] = (short)f2bf(v0.z); o[3] = (short)f2bf(v0.w);
            o[4] = (short)f2bf(v1.x); o[5] = (short)f2bf(v1.y);
            o[6] = (short)f2bf(v1.z); o[7] = (short)f2bf(v1.w);
        } else {
            o = (short8)(short)0;
        }
        *(short8*)(xb + idx) = o;
    }
}

// ---------------- GEMM: sup(bf16) = xb @ Wt, A via global_load_lds ----------
// BK=64: A-tile 128 rows x 128B = 16KB staged async (pre-swizzled source,
// linear LDS dest); afrag = swizzled ds_read_b128; B direct-global (L2-hot).
__global__ __launch_bounds__(256) void gcn_gemm(const unsigned short* __restrict__ xb,
                                                const unsigned short* __restrict__ wt,
                                                unsigned short* __restrict__ sup, int M) {
    __shared__ __align__(16) unsigned char As[16384];

    const int tid  = threadIdx.x;
    const int wv   = tid >> 6;
    const int lane = tid & 63;
    const int l15  = lane & 15;
    const int quad = lane >> 4;
    const int row0 = blockIdx.x * 128;

    float4v acc[2][8];
#pragma unroll
    for (int mt = 0; mt < 2; mt++)
#pragma unroll
        for (int nt = 0; nt < 8; nt++) acc[mt][nt] = (float4v)(0.f);

    for (int ks = 0; ks < 4; ks++) {
        // stage A-tile: 16 segments of 1KB; wave wv fills segments i*4+wv.
        // LDS linear; global source pre-swizzled (c = cp ^ ((row&7)<<4)).
#pragma unroll
        for (int i = 0; i < 4; i++) {
            int s   = i * 4 + wv;
            int off = (s << 10) + (lane << 4);     // lds byte this lane covers
            int row = off >> 7;                    // 0..127
            int cp  = off & 127;
            int c   = cp ^ ((row & 7) << 4);
            const char* src = (const char*)xb + (((long)(row0 + row)) << 9) + (ks << 7) + c;
            __builtin_amdgcn_global_load_lds((gld_src_t)(const void*)src,
                                             (gld_dst_t)(void*)(As + (s << 10)), 16, 0, 0);
        }
        __syncthreads();

#pragma unroll
        for (int subk = 0; subk < 2; subk++) {
            const int k0 = ks * 64 + subk * 32;
            short8 afrag[2];
#pragma unroll
            for (int mt = 0; mt < 2; mt++) {
                int row  = wv * 32 + mt * 16 + l15;
                int byte = (row << 7) + subk * 64 + quad * 16;
                byte ^= (row & 7) << 4;
                afrag[mt] = *(const short8*)(As + byte);
            }
            short8 bfrag[8];
#pragma unroll
            for (int nt = 0; nt < 8; nt++) {
                bfrag[nt] = *(const short8*)(wt + (nt * 16 + l15) * K_FEATS + k0 + quad * 8);
            }
#pragma unroll
            for (int mt = 0; mt < 2; mt++)
#pragma unroll
                for (int nt = 0; nt < 8; nt++)
                    acc[mt][nt] = __builtin_amdgcn_mfma_f32_16x16x32_bf16(
                        afrag[mt], bfrag[nt], acc[mt][nt], 0, 0, 0);
        }
        __syncthreads();
    }

#pragma unroll
    for (int mt = 0; mt < 2; mt++) {
#pragma unroll
        for (int reg = 0; reg < 4; reg++) {
            int grow = row0 + wv * 32 + mt * 16 + quad * 4 + reg;
            if (grow < M) {
#pragma unroll
                for (int nt = 0; nt < 8; nt++) {
                    sup[(long)grow * N_FEATS + nt * 16 + l15] = f2bf(acc[mt][nt][reg]);
                }
            }
        }
    }
}

// ---------------- fused sort+spmm: 512 threads per 128-row bucket -----------
__global__ __launch_bounds__(512) void bucket_spmm(const int* __restrict__ bcnt,
                                                   const int2* __restrict__ tmp,
                                                   const unsigned short* __restrict__ sup,
                                                   const float* __restrict__ b,
                                                   float* __restrict__ out, int M) {
    __shared__ int hist[BROWS];
    __shared__ int rs[BROWS];
    __shared__ int cur[BROWS];
    __shared__ __align__(16) int2 se[BCAP];      // 24 KB
    const int bkt  = blockIdx.x;
    const int tid  = threadIdx.x;
    const int wv   = tid >> 6;
    const int lane = tid & 63;
    const int row0 = bkt << BSHIFT;

    if (tid < BROWS) hist[tid] = 0;
    __syncthreads();

    int cnt = bcnt[bkt];
    if (cnt > BCAP) cnt = BCAP;
    const int2* t = tmp + (long)bkt * BCAP;

    int2 stash[STASH];
#pragma unroll
    for (int j = 0; j < STASH; j++) {
        int i = tid + j * 512;
        if (i < cnt) {
            int2 e = t[i];
            stash[j] = e;
            atomicAdd(&hist[(unsigned)e.x >> 17], 1);
        }
    }
    __syncthreads();

    if (tid < BROWS) cur[tid] = hist[tid];
    __syncthreads();
#pragma unroll
    for (int s = 1; s < BROWS; s <<= 1) {
        int v = 0;
        if (tid >= s && tid < BROWS) v = cur[tid - s];
        __syncthreads();
        if (tid < BROWS) cur[tid] += v;
        __syncthreads();
    }
    if (tid < BROWS) {
        int start = cur[tid] - hist[tid];        // exclusive
        rs[tid]  = start;
        cur[tid] = start;
    }
    __syncthreads();

#pragma unroll
    for (int j = 0; j < STASH; j++) {
        int i = tid + j * 512;
        if (i < cnt) {
            int2 e = stash[j];
            int rl = (unsigned)e.x >> 17;
            int p = atomicAdd(&cur[rl], 1);
            se[p] = make_int2(e.x & 0x1FFFF, e.y);
        }
    }
    __syncthreads();

    const int half = lane >> 5;
    const int l31  = lane & 31;
    const uint2* sup64 = (const uint2*)sup;      // 4 bf16 per uint2
    const float4v bb = ((const float4v*)b)[l31];

    for (int rr = 0; rr < 16; rr++) {
        int r    = wv * 16 + rr;
        int grow = row0 + r;
        if (grow >= M) break;
        int s  = rs[r];
        int e2 = s + hist[r];

        float4v acc = (float4v)(0.f);
        int base = s;
        for (; base + 8 <= e2; base += 8) {
            int2 ed[4];
#pragma unroll
            for (int u = 0; u < 4; u++) ed[u] = se[base + half + 2 * u];
            uint2 g[4];
#pragma unroll
            for (int u = 0; u < 4; u++) g[u] = sup64[(long)ed[u].x * 32 + l31];
#pragma unroll
            for (int u = 0; u < 4; u++) {
                float v = __int_as_float(ed[u].y);
                acc.x += v * __uint_as_float(g[u].x << 16);
                acc.y += v * __uint_as_float(g[u].x & 0xFFFF0000u);
                acc.z += v * __uint_as_float(g[u].y << 16);
                acc.w += v * __uint_as_float(g[u].y & 0xFFFF0000u);
            }
        }
        for (int i = base + half; i < e2; i += 2) {
            int2 ed = se[i];
            uint2 g = sup64[(long)ed.x * 32 + l31];
            float v = __int_as_float(ed.y);
            acc.x += v * __uint_as_float(g.x << 16);
            acc.y += v * __uint_as_float(g.x & 0xFFFF0000u);
            acc.z += v * __uint_as_float(g.y << 16);
            acc.w += v * __uint_as_float(g.y & 0xFFFF0000u);
        }

        acc.x += __shfl_xor(acc.x, 32);
        acc.y += __shfl_xor(acc.y, 32);
        acc.z += __shfl_xor(acc.z, 32);
        acc.w += __shfl_xor(acc.w, 32);

        if (half == 0) {
            float4v o = acc + bb;
            *(float4v*)(out + (long)grow * N_FEATS + l31 * 4) = o;
        }
    }
}

extern "C" void kernel_launch(void* const* d_in, const int* in_sizes, int n_in,
                              void* d_out, int out_size, void* d_ws, size_t ws_size,
                              hipStream_t stream) {
    const float* x     = (const float*)d_in[0];
    const int*   erow  = (const int*)d_in[1];
    const int*   ecol  = (const int*)d_in[2];
    const float* eval_ = (const float*)d_in[3];
    const float* w     = (const float*)d_in[4];
    const float* b     = (const float*)d_in[5];
    float* out = (float*)d_out;

    const int M   = in_sizes[0] / K_FEATS;     // 100000
    const int E   = in_sizes[1];               // 1600000
    const int NB  = (M + BROWS - 1) >> BSHIFT; // 782 (partition/spmm buckets)
    const int NT  = (M + 127) / 128;           // 782 gemm/convert tiles
    const int NCH = (E + CHUNK - 1) / CHUNK;   // 196 partition chunks

    // workspace layout (16B aligned)
    size_t o_sup  = 0;                                               // bf16 sup
    size_t o_xb   = o_sup  + (((size_t)M * N_FEATS * 2 + 15) & ~15ul);
    size_t o_wt   = o_xb   + ((size_t)NT * 128 * K_FEATS * 2);       // bf16 x (padded)
    size_t o_bcur = o_wt   + (size_t)K_FEATS * N_FEATS * 2;
    size_t o_tmp  = o_bcur + (((size_t)NB * 4 + 15) & ~15ul);

    unsigned short* sup  = (unsigned short*)((char*)d_ws + o_sup);
    unsigned short* xb   = (unsigned short*)((char*)d_ws + o_xb);
    unsigned short* wt   = (unsigned short*)((char*)d_ws + o_wt);
    int*            bcur = (int*)((char*)d_ws + o_bcur);
    int2*           tmp  = (int2*)((char*)d_ws + o_tmp);

    prep_w<<<N_FEATS, 256, 0, stream>>>(w, wt);
    zero_ints<<<(NB + 255) / 256, 256, 0, stream>>>(bcur, NB);

    // fused x->bf16 convert + edge partition (both memory-bound)
    conv_partition<<<NT + NCH, 256, 0, stream>>>(x, xb, M,
                                                 erow, ecol, eval_, bcur, tmp, E, NB, NCH);

    // pure-bf16 GEMM, A staged via global_load_lds
    gcn_gemm<<<NT, 256, 0, stream>>>(xb, wt, sup, M);

    // sort-in-LDS + gather + out, one kernel, no global sedge
    bucket_spmm<<<NB, 512, 0, stream>>>(bcur, tmp, sup, b, out, M);
}